// Round 1
// 2737.243 us; speedup vs baseline: 1.0606x; 1.0606x over previous
//
#include <hip/hip_runtime.h>
#include <hip/hip_bf16.h>
#include <stdint.h>

#define B_SZ 2048
#define U_SZ 1024
#define G_SZ 4096   // 4*U
#define I_SZ 256
#define O_SZ 256
#define T_SZ 96
#define K1_SZ 1280  // I + U

typedef _Float16 half8 __attribute__((ext_vector_type(8)));
typedef float float4v __attribute__((ext_vector_type(4)));

__device__ inline float sigm_f(float x) { return 1.0f / (1.0f + __expf(-x)); }
__device__ inline float tanh_f(float x) { return 1.0f - 2.0f / (1.0f + __expf(2.0f * x)); }

__device__ inline short f2h(float x) {
    return __builtin_bit_cast(short, (_Float16)x);
}

__device__ inline void cp16(const void* g, void* l) {
    __builtin_amdgcn_global_load_lds(
        (const __attribute__((address_space(1))) void*)g,
        (__attribute__((address_space(3))) void*)l,
        16, 0, 0);
}

// ---------------------------------------------------------------------------
// Prep kernels
// ---------------------------------------------------------------------------

// out[n][k] = in[k][c], n = 4*(c%1024) + c/1024   (gate interleave reorder)
__global__ void transpose_reord(const float* __restrict__ in, float* __restrict__ out, int K) {
    __shared__ float s[32][33];
    int c0 = blockIdx.x * 32, k0 = blockIdx.y * 32;
    int tx = threadIdx.x, ty = threadIdx.y;
#pragma unroll
    for (int i = 0; i < 4; i++)
        s[ty + 8 * i][tx] = in[(long)(k0 + ty + 8 * i) * G_SZ + c0 + tx];
    __syncthreads();
#pragma unroll
    for (int i = 0; i < 4; i++) {
        int cc = ty + 8 * i;
        int c = c0 + cc;
        int n = 4 * (c & 1023) + (c >> 10);
        out[(long)n * K + k0 + tx] = s[tx][cc];
    }
}

// plain f32 transpose: out[c][r] = in[r][c]; in [R][C]
__global__ void transpose_f32(const float* __restrict__ in, float* __restrict__ out, int R, int C) {
    __shared__ float s[32][33];
    int c0 = blockIdx.x * 32, r0 = blockIdx.y * 32;
    int tx = threadIdx.x, ty = threadIdx.y;
#pragma unroll
    for (int i = 0; i < 4; i++)
        s[ty + 8 * i][tx] = in[(long)(r0 + ty + 8 * i) * C + c0 + tx];
    __syncthreads();
#pragma unroll
    for (int i = 0; i < 4; i++)
        out[(long)(c0 + ty + 8 * i) * R + r0 + tx] = s[tx][ty + 8 * i];
}

// fp16 transpose: out[c][r] = fp16(in[r][c]); in [R][C] f32
__global__ void transpose_f16(const float* __restrict__ in, short* __restrict__ out, int R, int C) {
    __shared__ float s[32][33];
    int c0 = blockIdx.x * 32, r0 = blockIdx.y * 32;
    int tx = threadIdx.x, ty = threadIdx.y;
#pragma unroll
    for (int i = 0; i < 4; i++)
        s[ty + 8 * i][tx] = in[(long)(r0 + ty + 8 * i) * C + c0 + tx];
    __syncthreads();
#pragma unroll
    for (int i = 0; i < 4; i++)
        out[(long)(c0 + ty + 8 * i) * R + r0 + tx] = f2h(s[tx][ty + 8 * i]);
}

// elementwise f32 -> fp16 cast
__global__ void cast_f16(const float* __restrict__ in, short* __restrict__ out) {
    long i = (long)blockIdx.x * 256 + threadIdx.x;
    out[i] = f2h(in[i]);
}

// B0T[n][k] = fp16( k<256 ? WkT[n][k] : WrT[n][k-256] )   [4096][1280]
__global__ void build_b0t(const float* __restrict__ WkT, const float* __restrict__ WrT,
                          short* __restrict__ B0T) {
    long idx = (long)blockIdx.x * 256 + threadIdx.x;
    long n = idx / K1_SZ, k = idx % K1_SZ;
    float v = (k < I_SZ) ? WkT[n * I_SZ + k] : WrT[n * U_SZ + (k - I_SZ)];
    B0T[idx] = f2h(v);
}

// X0[m][k] = fp16( k<256 ? x0[m][k] : h0[m][k-256] )   [2048][1280]
__global__ void build_x0(const float* __restrict__ x0, const float* __restrict__ h0,
                         short* __restrict__ X0) {
    long idx = (long)blockIdx.x * 256 + threadIdx.x;
    long m = idx / K1_SZ, k = idx % K1_SZ;
    float v = (k < I_SZ) ? x0[m * I_SZ + k] : h0[m * U_SZ + (k - I_SZ)];
    X0[idx] = f2h(v);
}

// Gate-reordered biases, c = g*1024+j, slot 4j+g:
//   bR[4j+g]  = b[c]                        (t = 1: x_1 is the real input)
//   beR[4j+g] = b[c] + sum_p bd[p]*Wk[p][c] (t >= 2: x_t = h@Wd+bd folded in)
__global__ void build_ber(const float* __restrict__ Wk, const float* __restrict__ b,
                          const float* __restrict__ bd, float* __restrict__ beR,
                          float* __restrict__ bR) {
    int c = blockIdx.x * 256 + threadIdx.x;
    float s = 0.0f;
    for (int p = 0; p < I_SZ; p++) s += bd[p] * Wk[(long)p * G_SZ + c];
    int slot = 4 * (c & 1023) + (c >> 10);
    bR[slot] = b[c];
    beR[slot] = b[c] + s;
}

// ---------------------------------------------------------------------------
// Shared GEMM core: 256(A-rows) x 128(B-rows) tile, K-step 64, 8 waves.
// Triple-buffered LDS (3 x 48KB), counted vmcnt (never 0 in steady state),
// raw barriers with explicit lgkmcnt pin, setprio around MFMA clusters.
// A,B are fp16 K-major; gA/gB are per-thread pre-swizzled global pointers.
// Per wave: 64x64 output via 4x4 frags of 16x16x32. acc[mi][ni] layout:
// D row (A idx) = lk*4 + reg, D col (B idx) = lr.
// ---------------------------------------------------------------------------
__device__ __forceinline__ void gemm_core(char* smem, const char* gA, const char* gB,
                                          long Kb, int KI, int w, int l,
                                          float4v (&acc)[4][4]) {
    const int lr = l & 15, lk = l >> 4;
    const int wg = w >> 1, wb = w & 1;
    char* const lA = smem + (w * 32) * 128;           // wave stages A rows [w*32, w*32+32)
    char* const lB = smem + 32768 + (w * 16) * 128;   // wave stages B rows [w*16, w*16+16)

    auto stage = [&](int kt, int b) {
        const long go = (long)kt * 128;
        char* dA = lA + b * 49152;
        char* dB = lB + b * 49152;
#pragma unroll
        for (int ci = 0; ci < 4; ++ci) cp16(gA + (long)ci * 8 * Kb + go, dA + ci * 1024);
#pragma unroll
        for (int ci = 0; ci < 2; ++ci) cp16(gB + (long)ci * 8 * Kb + go, dB + ci * 1024);
    };
    auto compute = [&](int b) {
        const char* As = smem + b * 49152;
        const char* Bs = As + 32768;
#pragma unroll
        for (int ks = 0; ks < 2; ++ks) {
            half8 af[4], bf[4];
            const int chunk = (ks * 4 + lk) ^ (lr & 7);
#pragma unroll
            for (int mi = 0; mi < 4; ++mi)
                af[mi] = *(const half8*)(As + (wg * 64 + mi * 16 + lr) * 128 + chunk * 16);
#pragma unroll
            for (int ni = 0; ni < 4; ++ni)
                bf[ni] = *(const half8*)(Bs + (wb * 64 + ni * 16 + lr) * 128 + chunk * 16);
            __builtin_amdgcn_s_setprio(1);
#pragma unroll
            for (int mi = 0; mi < 4; ++mi)
#pragma unroll
                for (int ni = 0; ni < 4; ++ni)
                    acc[mi][ni] = __builtin_amdgcn_mfma_f32_16x16x32_f16(
                        af[mi], bf[ni], acc[mi][ni], 0, 0, 0);
            __builtin_amdgcn_s_setprio(0);
        }
    };

    // 6 loads/wave per stage. Depth-2 prefetch: tiles kt and kt+1 in flight.
    stage(0, 0);
    stage(1, 1);
    int bc = 0, bs = 2;  // compute buffer, stage buffer (kt%3, (kt+2)%3)
    for (int kt = 0; kt < KI; ++kt) {
        // tile kt landed <=> all but the newest 6 loads retired.
        // lgkmcnt(0) pins previous compute()'s ds_read sampling before the barrier
        // (MFMAs may sink past the barrier; their data must not).
        if (kt < KI - 1)
            asm volatile("s_waitcnt vmcnt(6) lgkmcnt(0)" ::: "memory");
        else
            asm volatile("s_waitcnt vmcnt(0) lgkmcnt(0)" ::: "memory");
        __builtin_amdgcn_s_barrier();
        asm volatile("" ::: "memory");
        // buffer bs last read at iter kt-1; all reads pinned before this barrier.
        if (kt + 2 < KI) stage(kt + 2, bs);
        compute(bc);
        bc = (bc == 2) ? 0 : bc + 1;
        bs = (bs == 2) ? 0 : bs + 1;
    }
}

// ---------------------------------------------------------------------------
// Main LSTM step: z^T-oriented GEMM + fused cell update.
// A [4096][K] fp16 (gate rows, reordered n=4j+g), Bm [2048][K] fp16 (batch rows)
// cT [1024][2048] f32 in/out, beR [1024][4], hOut [2048][1024] fp16
// grid (16 gate-tiles, 16 batch-tiles) = 256 blocks = 1/CU, block 512.
// ---------------------------------------------------------------------------
__global__ __launch_bounds__(512, 2) void lstm_step(
    const short* __restrict__ A, const short* __restrict__ Bm, int K,
    float* __restrict__ cT, const float* __restrict__ beR, short* __restrict__ hOut) {
    __shared__ char smem[147456];  // 3 x (32KB A-tile + 16KB B-tile)

    const int tid = threadIdx.x;
    const int w = tid >> 6, l = tid & 63;
    const int wg = w >> 1, wb = w & 1;
    const int n_blk = blockIdx.x, m_blk = blockIdx.y;
    const long Kb = (long)K * 2;

    float4v acc[4][4];
#pragma unroll
    for (int i = 0; i < 4; i++)
#pragma unroll
        for (int j = 0; j < 4; j++) acc[i][j] = (float4v)0.0f;

    const int r8 = l >> 3;        // row within 8-row chunk
    const int s8 = l & 7;         // 16B slot within row
    const int gch = s8 ^ r8;      // XOR swizzle (pre-swizzled global source)
    const char* gA = (const char*)A + ((long)(n_blk * 256 + w * 32 + r8)) * Kb + gch * 16;
    const char* gB = (const char*)Bm + ((long)(m_blk * 128 + w * 16 + r8)) * Kb + gch * 16;

    gemm_core(smem, gA, gB, Kb, K >> 6, w, l, acc);

    // Epilogue: lane's 4 regs of acc[mi][ni] are (zi,zf,zg,zo) of unit j, batch m
    const int lr = l & 15, lk = l >> 4;
    short* hs = (short*)smem;  // [128 m][64 j] fp16, XOR-swizzled, overlays buffers
    __syncthreads();           // all waves done reading LDS tiles before overwrite
    const int j_base = n_blk * 64 + wg * 16;
    const int m_base = m_blk * 128 + wb * 64;
#pragma unroll
    for (int mi = 0; mi < 4; ++mi) {
        int j = j_base + mi * 4 + lk;
        float4v bias = *(const float4v*)(beR + 4 * j);
#pragma unroll
        for (int ni = 0; ni < 4; ++ni) {
            int m = m_base + ni * 16 + lr;
            float zi = acc[mi][ni][0] + bias[0];
            float zf = acc[mi][ni][1] + bias[1];
            float zg = acc[mi][ni][2] + bias[2];
            float zo = acc[mi][ni][3] + bias[3];
            float ig = sigm_f(zi), fg = sigm_f(zf), gg = tanh_f(zg), og = sigm_f(zo);
            long cidx = (long)j * B_SZ + m;
            float cn = fg * cT[cidx] + ig * gg;
            cT[cidx] = cn;
            float h = og * tanh_f(cn);
            int mm = wb * 64 + ni * 16 + lr;
            int jj = wg * 16 + mi * 4 + lk;
            hs[mm * 64 + (jj ^ ((mm & 7) << 3))] = f2h(h);
        }
    }
    __syncthreads();
    // coalesced h write: 128 rows x 128B
    {
        const int q = tid & 7;
        int rr = tid >> 3;
#pragma unroll
        for (int it = 0; it < 2; ++it, rr += 64) {
            uint4 v = *(const uint4*)(hs + rr * 64 + ((q ^ (rr & 7)) * 8));
            *(uint4*)(hOut + (long)(m_blk * 128 + rr) * U_SZ + n_blk * 64 + q * 8) = v;
        }
    }
}

// ---------------------------------------------------------------------------
// Dense projection: out[b][t][o] = h[m][:] . WdT[o][:] + bd[o]
// Hm [M][1024] fp16, WdT [256][1024] fp16. grid (2, M/256) — o_blk is the
// fast dim so the two blocks sharing an Hm panel are dispatch-adjacent.
// t_fix<0: t = m>>11, b = m&2047 (history path)
// ---------------------------------------------------------------------------
__global__ __launch_bounds__(512, 2) void dense_out(
    const short* __restrict__ Hm, const short* __restrict__ WdT,
    const float* __restrict__ bd, float* __restrict__ out, int t_fix) {
    __shared__ char smem[147456];

    const int tid = threadIdx.x;
    const int w = tid >> 6, l = tid & 63;
    const int wg = w >> 1, wb = w & 1;
    const int o_blk = blockIdx.x, m_blk = blockIdx.y;
    const long Kb = U_SZ * 2;

    float4v acc[4][4];
#pragma unroll
    for (int i = 0; i < 4; i++)
#pragma unroll
        for (int j = 0; j < 4; j++) acc[i][j] = (float4v)0.0f;

    const int r8 = l >> 3, s8 = l & 7, gch = s8 ^ r8;
    const char* gA = (const char*)Hm + ((long)(m_blk * 256 + w * 32 + r8)) * Kb + gch * 16;
    const char* gB = (const char*)WdT + ((long)(o_blk * 128 + w * 16 + r8)) * Kb + gch * 16;

    gemm_core(smem, gA, gB, Kb, U_SZ >> 6, w, l, acc);

    const int lr = l & 15, lk = l >> 4;
#pragma unroll
    for (int ni = 0; ni < 4; ++ni) {
        int o = o_blk * 128 + wb * 64 + ni * 16 + lr;
        float bo = bd[o];
#pragma unroll
        for (int mi = 0; mi < 4; ++mi) {
#pragma unroll
            for (int r = 0; r < 4; ++r) {
                int m = m_blk * 256 + wg * 64 + mi * 16 + lk * 4 + r;
                int t = (t_fix >= 0) ? t_fix : (m >> 11);
                int b = (t_fix >= 0) ? m : (m & 2047);
                out[(long)b * (T_SZ * O_SZ) + (long)t * O_SZ + o] = acc[mi][ni][r] + bo;
            }
        }
    }
}

// ---------------------------------------------------------------------------
// Weight fold (MFMA): WeT[n][k] = fp16( WrT[n][k] + sum_p WkTh[n][p]*Wdh[k][p] )
// WkTh [4096][256] fp16, Wdh [1024][256] fp16, WrT [4096][1024] f32
// grid (16, 8), block 512.
// ---------------------------------------------------------------------------
__global__ __launch_bounds__(512, 2) void fold_mfma(
    const short* __restrict__ WkTh, const short* __restrict__ Wdh,
    const float* __restrict__ WrT, short* __restrict__ WeT) {
    __shared__ char smem[147456];

    const int tid = threadIdx.x;
    const int w = tid >> 6, l = tid & 63;
    const int wg = w >> 1, wb = w & 1;
    const int n_blk = blockIdx.x, k_blk = blockIdx.y;
    const long Kb = I_SZ * 2;

    float4v acc[4][4];
#pragma unroll
    for (int i = 0; i < 4; i++)
#pragma unroll
        for (int j = 0; j < 4; j++) acc[i][j] = (float4v)0.0f;

    const int r8 = l >> 3, s8 = l & 7, gch = s8 ^ r8;
    const char* gA = (const char*)WkTh + ((long)(n_blk * 256 + w * 32 + r8)) * Kb + gch * 16;
    const char* gB = (const char*)Wdh + ((long)(k_blk * 128 + w * 16 + r8)) * Kb + gch * 16;

    gemm_core(smem, gA, gB, Kb, I_SZ >> 6, w, l, acc);

    const int lr = l & 15, lk = l >> 4;
#pragma unroll
    for (int mi = 0; mi < 4; ++mi)
#pragma unroll
        for (int ni = 0; ni < 4; ++ni)
#pragma unroll
            for (int r = 0; r < 4; ++r) {
                long n = n_blk * 256 + wg * 64 + mi * 16 + lk * 4 + r;
                long k = k_blk * 128 + wb * 64 + ni * 16 + lr;
                WeT[n * U_SZ + k] = f2h(WrT[n * U_SZ + k] + acc[mi][ni][r]);
            }
}

// ---------------------------------------------------------------------------
extern "C" void kernel_launch(void* const* d_in, const int* in_sizes, int n_in,
                              void* d_out, int out_size, void* d_ws, size_t ws_size,
                              hipStream_t stream) {
    (void)in_sizes; (void)n_in; (void)out_size;
    const float* x0 = (const float*)d_in[0];
    const float* h0 = (const float*)d_in[1];
    const float* c0 = (const float*)d_in[2];
    const float* Wk = (const float*)d_in[3];
    const float* Wr = (const float*)d_in[4];
    const float* bb = (const float*)d_in[5];
    const float* Wd = (const float*)d_in[6];
    const float* bd = (const float*)d_in[7];
    float* out = (float*)d_out;

    char* p = (char*)d_ws;
    auto alloc = [&](size_t bytes) {
        char* r = p;
        p += (bytes + 255) & ~(size_t)255;
        return r;
    };
    short* WeT = (short*)alloc((size_t)G_SZ * U_SZ * 2);
    short* B0T = (short*)alloc((size_t)G_SZ * K1_SZ * 2);
    short* X0 = (short*)alloc((size_t)B_SZ * K1_SZ * 2);
    short* WdT = (short*)alloc((size_t)O_SZ * U_SZ * 2);
    short* WkTh = (short*)alloc((size_t)G_SZ * I_SZ * 2);
    short* Wdh = (short*)alloc((size_t)U_SZ * I_SZ * 2);
    float* beR = (float*)alloc((size_t)U_SZ * 4 * 4);
    float* bR = (float*)alloc((size_t)U_SZ * 4 * 4);
    float* cT = (float*)alloc((size_t)U_SZ * B_SZ * 4);
    char* R = p;
    const size_t SLAB = (size_t)B_SZ * U_SZ * 2;  // 4 MB fp16 h-state
    size_t rem = (ws_size > (size_t)(R - (char*)d_ws)) ? ws_size - (size_t)(R - (char*)d_ws) : 0;
    bool hist = rem >= (size_t)T_SZ * SLAB;

    // fp32 transposes alias the slab region (prep-only, all reads finish before step 1)
    float* WkT = (float*)R;
    float* WrT = (float*)(R + (size_t)G_SZ * I_SZ * 4);

    transpose_reord<<<dim3(G_SZ / 32, I_SZ / 32), dim3(32, 8), 0, stream>>>(Wk, WkT, I_SZ);
    transpose_reord<<<dim3(G_SZ / 32, U_SZ / 32), dim3(32, 8), 0, stream>>>(Wr, WrT, U_SZ);
    cast_f16<<<(G_SZ * I_SZ) / 256, 256, 0, stream>>>(WkT, WkTh);
    cast_f16<<<(U_SZ * I_SZ) / 256, 256, 0, stream>>>(Wd, Wdh);
    fold_mfma<<<dim3(G_SZ / 256, U_SZ / 128), 512, 0, stream>>>(WkTh, Wdh, WrT, WeT);
    build_b0t<<<(int)(((size_t)G_SZ * K1_SZ) / 256), 256, 0, stream>>>(WkT, WrT, B0T);
    build_ber<<<G_SZ / 256, 256, 0, stream>>>(Wk, bb, bd, beR, bR);
    transpose_f16<<<dim3(O_SZ / 32, U_SZ / 32), dim3(32, 8), 0, stream>>>(Wd, WdT, U_SZ, O_SZ);
    transpose_f32<<<dim3(U_SZ / 32, B_SZ / 32), dim3(32, 8), 0, stream>>>(c0, cT, B_SZ, U_SZ);
    build_x0<<<(int)(((size_t)B_SZ * K1_SZ) / 256), 256, 0, stream>>>(x0, h0, X0);

    auto slab = [&](int t) -> short* {  // t in 1..96
        if (hist) return (short*)(R + (size_t)(t - 1) * SLAB);
        return (short*)(R + (size_t)((t - 1) & 1) * SLAB);
    };

    for (int t = 1; t <= T_SZ; ++t) {
        if (t == 1)
            lstm_step<<<dim3(G_SZ / 256, B_SZ / 128), 512, 0, stream>>>(
                B0T, X0, K1_SZ, cT, bR, slab(1));  // plain bias: x_1 is the real input
        else
            lstm_step<<<dim3(G_SZ / 256, B_SZ / 128), 512, 0, stream>>>(
                WeT, slab(t - 1), U_SZ, cT, beR, slab(t));
        if (!hist)
            dense_out<<<dim3(2, B_SZ / 256), 512, 0, stream>>>(slab(t), WdT, bd, out, t - 1);
    }
    if (hist)
        dense_out<<<dim3(2, (T_SZ * B_SZ) / 256), 512, 0, stream>>>((short*)R, WdT, bd, out, -1);
}